// Round 2
// baseline (402.897 us; speedup 1.0000x reference)
//
#include <hip/hip_runtime.h>
#include <hip/hip_bf16.h>

typedef unsigned short u16;
typedef unsigned int u32;
typedef short short8 __attribute__((ext_vector_type(8)));
typedef float fx4 __attribute__((ext_vector_type(4)));
typedef u32 ux4 __attribute__((ext_vector_type(4)));

__device__ __forceinline__ float b2f(u16 x) {
  return __uint_as_float(((u32)x) << 16);
}
__device__ __forceinline__ u16 f2b(float f) {
  u32 u = __float_as_uint(f);
  u += 0x7fffu + ((u >> 16) & 1u);  // RNE
  return (u16)(u >> 16);
}
// HW packed f32x2 -> bf16x2 (RNE). No builtin on gfx950; inline asm per T12.
__device__ __forceinline__ u32 cvtpk(float a, float b) {
  u32 r;
  asm("v_cvt_pk_bf16_f32 %0, %1, %2" : "=v"(r) : "v"(a), "v"(b));
  return r;
}

// Async global->LDS DMA, 16B per lane. LDS dest = wave-uniform base + lane*16.
__device__ __forceinline__ void load16(const u16* g, u16* l) {
  __builtin_amdgcn_global_load_lds(
      (__attribute__((address_space(1))) void*)(u16*)g,
      (__attribute__((address_space(3))) void*)l, 16, 0, 0);
}

// ---------------------------------------------------------------------------
// f32 -> bf16 elementwise. grid = n/1024, block 256 (4 elems/thread).
// ---------------------------------------------------------------------------
__global__ __launch_bounds__(256) void cvt_f2b_kernel(
    const float* __restrict__ in, u16* __restrict__ out)
{
  int i = (blockIdx.x * 256 + threadIdx.x) * 4;
  fx4 v = *(const fx4*)(in + i);
  u16 o4[4];
#pragma unroll
  for (int j = 0; j < 4; ++j) o4[j] = f2b(v[j]);
  *(uint2*)(out + i) = *(uint2*)o4;
}

// ---------------------------------------------------------------------------
// Fused transpose + f32->bf16: out[batch][c][r] = bf16(in[batch][r][c]).
// grid: (C/32, R/32, nbatch), block: (32,8). out batch stride = C * out_ld.
// ---------------------------------------------------------------------------
__global__ __launch_bounds__(256) void transpose_f2b_kernel(
    const float* __restrict__ in, u16* __restrict__ out,
    int R, int C, int out_ld)
{
  __shared__ __align__(16) u16 tile[32][33];
  int tx = threadIdx.x, ty = threadIdx.y;
  int c0 = blockIdx.x * 32, r0 = blockIdx.y * 32;
  const float* inb = in + (size_t)blockIdx.z * R * C;
  u16* outb = out + (size_t)blockIdx.z * C * out_ld;
#pragma unroll
  for (int i = 0; i < 4; ++i)
    tile[ty + i * 8][tx] = f2b(inb[(size_t)(r0 + ty + i * 8) * C + c0 + tx]);
  __syncthreads();
#pragma unroll
  for (int i = 0; i < 4; ++i)
    outb[(size_t)(c0 + ty + i * 8) * out_ld + r0 + tx] = tile[tx][ty + i * 8];
}

// ---------------------------------------------------------------------------
// bf16 strided transpose: out[c][r] = in[r*in_ld + c]. grid (C/32, R/32).
// ---------------------------------------------------------------------------
__global__ __launch_bounds__(256) void transpose_b2b_kernel(
    const u16* __restrict__ in, u16* __restrict__ out, int in_ld, int out_ld)
{
  __shared__ __align__(16) u16 tile[32][33];
  int tx = threadIdx.x, ty = threadIdx.y;
  int c0 = blockIdx.x * 32, r0 = blockIdx.y * 32;
#pragma unroll
  for (int i = 0; i < 4; ++i)
    tile[ty + i * 8][tx] = in[(size_t)(r0 + ty + i * 8) * in_ld + c0 + tx];
  __syncthreads();
#pragma unroll
  for (int i = 0; i < 4; ++i)
    out[(size_t)(c0 + ty + i * 8) * out_ld + r0 + tx] = tile[tx][ty + i * 8];
}

// ---------------------------------------------------------------------------
// C[M,N] = A[M,K] * BT[N,K]^T; bf16 in, fp32 acc. 128x128 tile, BK=32,
// 4 waves x 64x64. global_load_lds dbuf staging, 1 barrier/K-tile, XOR swizzle.
// flags: 1 = store bf16 (else fp32), 2 = add f32 bias[col], 4 = relu.
// ---------------------------------------------------------------------------
__global__ __launch_bounds__(256, 2) void gemm_bt(
    const u16* __restrict__ A, const u16* __restrict__ BT,
    const float* __restrict__ bias, void* __restrict__ Cp,
    int M, int N, int K, int flags)
{
  __shared__ __align__(16) u16 As[2][4096];
  __shared__ __align__(16) u16 Bs[2][4096];
  int tid = threadIdx.x;
  int lane = tid & 63, wid = tid >> 6;
  int l15 = lane & 15, quad = lane >> 4;
  int wm = wid >> 1, wn = wid & 1;
  int m0 = blockIdx.y * 128, n0 = blockIdx.x * 128;

  int srow = wid * 16 + (lane >> 2);
  int sswz = (((lane >> 2) & 3) + ((lane >> 4) & 3)) & 3;
  int gch = (lane & 3) ^ sswz;
  const u16* gA = A + (size_t)(m0 + srow) * K + gch * 8;
  const u16* gB = BT + (size_t)(n0 + srow) * K + gch * 8;
  size_t gstep = (size_t)64 * K;
  u16* lA = &As[0][wid * 512];
  u16* lB = &Bs[0][wid * 512];

  int rswz = ((l15 & 3) + (l15 >> 2)) & 3;
  int rphys = ((quad ^ rswz) & 3) << 3;

  fx4 acc[4][4];
#pragma unroll
  for (int i = 0; i < 4; ++i)
#pragma unroll
    for (int j = 0; j < 4; ++j) acc[i][j] = fx4{0.f, 0.f, 0.f, 0.f};

  int nt = K >> 5;
  load16(gA,         lA);
  load16(gA + gstep, lA + 2048);
  load16(gB,         lB);
  load16(gB + gstep, lB + 2048);

  for (int kt = 0; kt < nt; ++kt) {
    __syncthreads();
    if (kt + 1 < nt) {
      int buf = (kt + 1) & 1;
      const u16* ga = gA + (kt + 1) * 32;
      const u16* gb = gB + (kt + 1) * 32;
      load16(ga,         lA + buf * 4096);
      load16(ga + gstep, lA + buf * 4096 + 2048);
      load16(gb,         lB + buf * 4096);
      load16(gb + gstep, lB + buf * 4096 + 2048);
    }
    const u16* Ab = As[kt & 1];
    const u16* Bb = Bs[kt & 1];
    short8 af[4], bf[4];
#pragma unroll
    for (int t = 0; t < 4; ++t)
      af[t] = *(const short8*)&Ab[(wm * 64 + t * 16 + l15) * 32 + rphys];
#pragma unroll
    for (int t = 0; t < 4; ++t)
      bf[t] = *(const short8*)&Bb[(wn * 64 + t * 16 + l15) * 32 + rphys];
#pragma unroll
    for (int tm = 0; tm < 4; ++tm)
#pragma unroll
      for (int tn = 0; tn < 4; ++tn)
        acc[tm][tn] = __builtin_amdgcn_mfma_f32_16x16x32_bf16(
            af[tm], bf[tn], acc[tm][tn], 0, 0, 0);
  }

  bool obf = flags & 1, hb = flags & 2, rl = flags & 4;
#pragma unroll
  for (int tn = 0; tn < 4; ++tn) {
    int col = n0 + wn * 64 + tn * 16 + l15;
    float bv = hb ? bias[col] : 0.0f;
#pragma unroll
    for (int tm = 0; tm < 4; ++tm) {
      int row = m0 + wm * 64 + tm * 16 + (quad << 2);
#pragma unroll
      for (int r = 0; r < 4; ++r) {
        float v = acc[tm][tn][r] + bv;
        if (rl) v = fmaxf(v, 0.0f);
        size_t idx = (size_t)(row + r) * N + col;
        if (obf) ((u16*)Cp)[idx] = f2b(v);
        else ((float*)Cp)[idx] = v;
      }
    }
  }
}

// ---------------------------------------------------------------------------
// 128M x 64N tile variant for small-N GEMMs, with split-K over blockIdx.z.
// Each z-chunk computes C_z = A[:, z*kc:(z+1)*kc] * BT[:, same]^T and writes
// its own f32 partial buffer at Cp + z*M*N floats (summed later in ln_kernel).
// 4 waves x 64x32 (4x2 mfma tiles), 24 KB LDS -> 4+ blocks/CU co-resident.
// grid: (N/64, M/128, nsplit). Same flags as gemm_bt.
// ---------------------------------------------------------------------------
__global__ __launch_bounds__(256, 2) void gemm_bt_n64(
    const u16* __restrict__ A, const u16* __restrict__ BT,
    const float* __restrict__ bias, void* __restrict__ Cp,
    int M, int N, int K, int flags)
{
  __shared__ __align__(16) u16 As[2][4096];
  __shared__ __align__(16) u16 Bs[2][2048];
  int tid = threadIdx.x;
  int lane = tid & 63, wid = tid >> 6;
  int l15 = lane & 15, quad = lane >> 4;
  int wm = wid >> 1, wn = wid & 1;
  int m0 = blockIdx.y * 128, n0 = blockIdx.x * 64;
  int zz = blockIdx.z;
  int kc = K / (int)gridDim.z;  // K-chunk length (multiple of 32)

  int srow = wid * 16 + (lane >> 2);
  int sswz = (((lane >> 2) & 3) + ((lane >> 4) & 3)) & 3;
  int gch = (lane & 3) ^ sswz;
  const u16* gA = A + (size_t)(m0 + srow) * K + zz * kc + gch * 8;
  const u16* gB = BT + (size_t)(n0 + srow) * K + zz * kc + gch * 8;
  size_t gstep = (size_t)64 * K;
  u16* lA = &As[0][wid * 512];
  u16* lB = &Bs[0][wid * 512];

  int rswz = ((l15 & 3) + (l15 >> 2)) & 3;
  int rphys = ((quad ^ rswz) & 3) << 3;

  fx4 acc[4][2];
#pragma unroll
  for (int i = 0; i < 4; ++i)
#pragma unroll
    for (int j = 0; j < 2; ++j) acc[i][j] = fx4{0.f, 0.f, 0.f, 0.f};

  int nt = kc >> 5;
  load16(gA,         lA);
  load16(gA + gstep, lA + 2048);
  load16(gB,         lB);

  for (int kt = 0; kt < nt; ++kt) {
    __syncthreads();
    if (kt + 1 < nt) {
      int buf = (kt + 1) & 1;
      const u16* ga = gA + (kt + 1) * 32;
      const u16* gb = gB + (kt + 1) * 32;
      load16(ga,         lA + buf * 4096);
      load16(ga + gstep, lA + buf * 4096 + 2048);
      load16(gb,         lB + buf * 2048);
    }
    const u16* Ab = As[kt & 1];
    const u16* Bb = Bs[kt & 1];
    short8 af[4], bf[2];
#pragma unroll
    for (int t = 0; t < 4; ++t)
      af[t] = *(const short8*)&Ab[(wm * 64 + t * 16 + l15) * 32 + rphys];
#pragma unroll
    for (int t = 0; t < 2; ++t)
      bf[t] = *(const short8*)&Bb[(wn * 32 + t * 16 + l15) * 32 + rphys];
#pragma unroll
    for (int tm = 0; tm < 4; ++tm)
#pragma unroll
      for (int tn = 0; tn < 2; ++tn)
        acc[tm][tn] = __builtin_amdgcn_mfma_f32_16x16x32_bf16(
            af[tm], bf[tn], acc[tm][tn], 0, 0, 0);
  }

  bool obf = flags & 1, hb = flags & 2, rl = flags & 4;
  u16* cb16 = (u16*)Cp + (size_t)zz * M * N;
  float* cf32 = (float*)Cp + (size_t)zz * M * N;
#pragma unroll
  for (int tn = 0; tn < 2; ++tn) {
    int col = n0 + wn * 32 + tn * 16 + l15;
    float bv = hb ? bias[col] : 0.0f;
#pragma unroll
    for (int tm = 0; tm < 4; ++tm) {
      int row = m0 + wm * 64 + tm * 16 + (quad << 2);
#pragma unroll
      for (int r = 0; r < 4; ++r) {
        float v = acc[tm][tn][r] + bv;
        if (rl) v = fmaxf(v, 0.0f);
        size_t idx = (size_t)(row + r) * N + col;
        if (obf) cb16[idx] = f2b(v);
        else cf32[idx] = v;
      }
    }
  }
}

// ---------------------------------------------------------------------------
// Flash attention v2, in-register P (no LDS round-trip).
// qkv[4096][3072] bf16 (q|k|v); vT[1024][4096] bf16; o[4096][1024] bf16.
// grid: (S/64, H, B); block 256. 64-key tiles, global_load_lds dbuf.
// QK^T computed SWAPPED (mfma(K,Q)) so P[key][q=l15] is lane-local; the 16
// p-values cvt_pk directly into the PV A-fragment under a permuted key axis
// (key k of A-slot (quad,j): j<2 -> 4*quad+2j, j>=2 -> 16+4*quad+2(j-2));
// V is read with matching ds_read_b64 half-chunks so the permutation cancels.
// Row sums: per-lane f32 accumulate + shfl reduce at the end (no ones-MFMA).
// ---------------------------------------------------------------------------
__global__ __launch_bounds__(256) void attn_kernel(
    const u16* __restrict__ qkv, const u16* __restrict__ vT,
    u16* __restrict__ o)
{
  __shared__ __align__(16) u16 Ks[2][4096];
  __shared__ __align__(16) u16 Vs[2][4096];
  int tid = threadIdx.x;
  int lane = tid & 63, wid = tid >> 6;
  int l15 = lane & 15, quad = lane >> 4;
  int b = blockIdx.z, h = blockIdx.y;
  int q0 = blockIdx.x * 64 + wid * 16;

  const u16* qb = qkv + (size_t)(b * 2048 + q0 + l15) * 3072 + h * 64 + (quad << 3);
  short8 qf0 = *(const short8*)qb;
  short8 qf1 = *(const short8*)(qb + 32);

  int srow = tid >> 3;
  int gc8 = ((tid & 7) ^ (srow & 7)) << 3;
  const u16* kg = qkv + (size_t)(b * 2048 + srow) * 3072 + 1024 + h * 64 + gc8;
  const u16* vg = vT + (size_t)(h * 64 + srow) * 4096 + b * 2048 + gc8;
  u16* lk = &Ks[0][wid * 512];
  u16* lv = &Vs[0][wid * 512];

  fx4 oacc[4];
  float suml = 0.0f;
#pragma unroll
  for (int i = 0; i < 4; ++i) oacc[i] = fx4{0.f, 0.f, 0.f, 0.f};

  load16(kg,             lk);
  load16(kg + 32 * 3072, lk + 2048);
  load16(vg,             lv);
  load16(vg + 32 * 4096, lv + 2048);

  int swz = l15 & 7;
  int q2 = quad >> 1;          // V 16B-chunk selector
  int h4 = (quad & 1) * 4;     // V half-chunk (8B) selector, in u16 units
  for (int kt = 0; kt < 32; ++kt) {
    __syncthreads();
    if (kt + 1 < 32) {
      int buf = (kt + 1) & 1;
      const u16* kgn = kg + (size_t)(kt + 1) * 64 * 3072;
      const u16* vgn = vg + (kt + 1) * 64;
      load16(kgn,             lk + buf * 4096);
      load16(kgn + 32 * 3072, lk + buf * 4096 + 2048);
      load16(vgn,             lv + buf * 4096);
      load16(vgn + 32 * 4096, lv + buf * 4096 + 2048);
    }
    const u16* Kb = Ks[kt & 1];
    const u16* Vb = Vs[kt & 1];

    // QK^T swapped: sc[sub][r] = S[key = sub*16 + quad*4 + r][q = l15]
    fx4 sc[4];
#pragma unroll
    for (int sub = 0; sub < 4; ++sub) {
      sc[sub] = fx4{0.f, 0.f, 0.f, 0.f};
      const u16* rp = &Kb[(sub * 16 + l15) * 64];
      short8 kf0 = *(const short8*)&rp[((quad ^ swz) & 7) << 3];
      short8 kf1 = *(const short8*)&rp[(((4 | quad) ^ swz) & 7) << 3];
      sc[sub] = __builtin_amdgcn_mfma_f32_16x16x32_bf16(kf0, qf0, sc[sub], 0, 0, 0);
      sc[sub] = __builtin_amdgcn_mfma_f32_16x16x32_bf16(kf1, qf1, sc[sub], 0, 0, 0);
    }

    // softmax numerators straight into PV A-fragments (in-register)
    u32 W[4][2];
    float ps = 0.0f;
#pragma unroll
    for (int sub = 0; sub < 4; ++sub) {
      float p0 = __expf(sc[sub][0] * 0.125f);
      float p1 = __expf(sc[sub][1] * 0.125f);
      float p2 = __expf(sc[sub][2] * 0.125f);
      float p3 = __expf(sc[sub][3] * 0.125f);
      ps += (p0 + p1) + (p2 + p3);
      W[sub][0] = cvtpk(p0, p1);
      W[sub][1] = cvtpk(p2, p3);
    }
    suml += ps;
    short8 pa1 = __builtin_bit_cast(short8, ux4{W[0][0], W[0][1], W[1][0], W[1][1]});
    short8 pa2 = __builtin_bit_cast(short8, ux4{W[2][0], W[2][1], W[3][0], W[3][1]});

#pragma unroll
    for (int dt = 0; dt < 4; ++dt) {
      const u16* rp = &Vb[(dt * 16 + l15) * 64];
      uint2 v0a = *(const uint2*)&rp[(((q2)     ^ swz) << 3) + h4];
      uint2 v0b = *(const uint2*)&rp[(((2 + q2) ^ swz) << 3) + h4];
      uint2 v1a = *(const uint2*)&rp[(((4 + q2) ^ swz) << 3) + h4];
      uint2 v1b = *(const uint2*)&rp[(((6 + q2) ^ swz) << 3) + h4];
      short8 vf0 = __builtin_bit_cast(short8, ux4{v0a.x, v0a.y, v0b.x, v0b.y});
      short8 vf1 = __builtin_bit_cast(short8, ux4{v1a.x, v1a.y, v1b.x, v1b.y});
      oacc[dt] = __builtin_amdgcn_mfma_f32_16x16x32_bf16(pa1, vf0, oacc[dt], 0, 0, 0);
      oacc[dt] = __builtin_amdgcn_mfma_f32_16x16x32_bf16(pa2, vf1, oacc[dt], 0, 0, 0);
    }
  }
  // denominator: reduce the 4 quads sharing each l15, then fetch per-row
  suml += __shfl_xor(suml, 16, 64);
  suml += __shfl_xor(suml, 32, 64);
  fx4 inv;
#pragma unroll
  for (int r = 0; r < 4; ++r)
    inv[r] = 1.0f / __shfl(suml, (quad << 2) + r, 64);
#pragma unroll
  for (int dt = 0; dt < 4; ++dt) {
    int col = h * 64 + dt * 16 + l15;
#pragma unroll
    for (int r = 0; r < 4; ++r)
      o[(size_t)(b * 2048 + q0 + (quad << 2) + r) * 1024 + col] =
          f2b(oacc[dt][r] * inv[r]);
  }
}

// ---------------------------------------------------------------------------
// LN: LayerNorm(main0 + main1 + res + cbias[col]) * g + beta, row len 1024.
// main1 is the second split-K partial (always present); cbias nullable
// (folds the FFN2 column bias in, since the GEMM now emits raw partials).
// ---------------------------------------------------------------------------
__global__ __launch_bounds__(256) void ln_kernel(
    const float* __restrict__ main0, const float* __restrict__ main1,
    const float* __restrict__ res, const float* __restrict__ cbias,
    const float* __restrict__ g, const float* __restrict__ beta,
    u16* __restrict__ out_b, float* __restrict__ out_f)
{
  __shared__ float red[8];
  int row = blockIdx.x, tid = threadIdx.x;
  size_t base = (size_t)row * 1024 + tid * 4;
  fx4 v = *(const fx4*)(main0 + base);
  fx4 v1 = *(const fx4*)(main1 + base);
  fx4 rv = *(const fx4*)(res + base);
#pragma unroll
  for (int i = 0; i < 4; ++i) v[i] += v1[i] + rv[i];
  if (cbias) {
    fx4 cb = *(const fx4*)(cbias + tid * 4);
#pragma unroll
    for (int i = 0; i < 4; ++i) v[i] += cb[i];
  }
  float s = v[0] + v[1] + v[2] + v[3];
  float sq = v[0] * v[0] + v[1] * v[1] + v[2] * v[2] + v[3] * v[3];
#pragma unroll
  for (int off = 32; off >= 1; off >>= 1) {
    s += __shfl_xor(s, off, 64);
    sq += __shfl_xor(sq, off, 64);
  }
  int wid = tid >> 6, lane = tid & 63;
  if (lane == 0) { red[wid] = s; red[wid + 4] = sq; }
  __syncthreads();
  float S = red[0] + red[1] + red[2] + red[3];
  float SQ = red[4] + red[5] + red[6] + red[7];
  float mean = S * (1.0f / 1024.0f);
  float var = SQ * (1.0f / 1024.0f) - mean * mean;
  float rs = rsqrtf(var + 1e-5f);
  fx4 gv = *(const fx4*)(g + tid * 4);
  fx4 bv = *(const fx4*)(beta + tid * 4);
  float of[4];
#pragma unroll
  for (int i = 0; i < 4; ++i) of[i] = (v[i] - mean) * rs * gv[i] + bv[i];
  if (out_f) *(fx4*)(out_f + base) = *(const fx4*)of;
  if (out_b) {
    u16 o4[4];
#pragma unroll
    for (int i = 0; i < 4; ++i) o4[i] = f2b(of[i]);
    *(uint2*)(out_b + base) = *(uint2*)o4;
  }
}

// ---------------------------------------------------------------------------
// Workspace (peak 88 MiB, liveness-checked):
//   xb    bf16 [ 0, 8)M   (dead after QKV gemm)
//   wqkvT bf16 [ 8,14)M   (dead after QKV gemm)
//   woT   bf16 [38,40)M   (dead after Wo-proj)
//   qkv   bf16 [40,64)M   (dead after attn)
//   vT    bf16 [64,72)M   (dead after attn)
//   ob    bf16 [72,80)M   (dead after Wo-proj)
//   aout  f32  [ 0,32)M   2 split-K partials (dead after LN1)
//   x1f   f32  [40,56)M   (live until LN2)
//   x1    bf16 [64,72)M   (dead after FFN1)
//   w1T   bf16 [56,64)M   (dead after FFN1)
//   w2T   bf16 [ 0, 8)M   (live until FFN2)
//   hbuf  bf16 [ 8,40)M   (live until FFN2)
//   ffn   f32  [56,88)M   2 split-K partials (live until LN2)
// ---------------------------------------------------------------------------
extern "C" void kernel_launch(void* const* d_in, const int* in_sizes, int n_in,
                              void* d_out, int out_size, void* d_ws, size_t ws_size,
                              hipStream_t stream) {
  (void)in_sizes; (void)n_in; (void)out_size; (void)ws_size;
  const float* x     = (const float*)d_in[0];
  const float* Wq    = (const float*)d_in[1];
  const float* Wk    = (const float*)d_in[2];
  const float* Wv    = (const float*)d_in[3];
  const float* Wo    = (const float*)d_in[4];
  const float* g1    = (const float*)d_in[5];
  const float* bb1   = (const float*)d_in[6];
  const float* W1    = (const float*)d_in[7];
  const float* bias1 = (const float*)d_in[8];
  const float* W2    = (const float*)d_in[9];
  const float* bias2 = (const float*)d_in[10];
  const float* g2    = (const float*)d_in[11];
  const float* bb2   = (const float*)d_in[12];

  char* ws = (char*)d_ws;
  const size_t MB = 1048576;
  u16* xb     = (u16*)(ws);
  u16* wqkvT  = (u16*)(ws + 8 * MB);
  u16* woT    = (u16*)(ws + 38 * MB);
  u16* qkv    = (u16*)(ws + 40 * MB);
  u16* vT     = (u16*)(ws + 64 * MB);
  u16* ob     = (u16*)(ws + 72 * MB);
  float* aout = (float*)(ws);            // 2 partials, 16MB each
  u16* x1     = (u16*)(ws + 64 * MB);
  float* x1f  = (float*)(ws + 40 * MB);
  u16* w1T    = (u16*)(ws + 56 * MB);
  u16* w2T    = (u16*)(ws);
  u16* hbuf   = (u16*)(ws + 8 * MB);
  float* ffn  = (float*)(ws + 56 * MB);  // 2 partials, 16MB each

  dim3 tb(32, 8, 1);
  cvt_f2b_kernel<<<4096, 256, 0, stream>>>(x, xb);
  transpose_f2b_kernel<<<dim3(2, 32, 16), tb, 0, stream>>>(Wq, wqkvT,           1024, 64, 1024);
  transpose_f2b_kernel<<<dim3(2, 32, 16), tb, 0, stream>>>(Wk, wqkvT + 1048576, 1024, 64, 1024);
  transpose_f2b_kernel<<<dim3(2, 32, 16), tb, 0, stream>>>(Wv, wqkvT + 2097152, 1024, 64, 1024);
  transpose_f2b_kernel<<<dim3(32, 32, 1), tb, 0, stream>>>(Wo, woT, 1024, 1024, 1024);

  // qkv = x @ [Wq|Wk|Wv]  (bf16 out)
  gemm_bt<<<dim3(24, 32), 256, 0, stream>>>(xb, wqkvT, nullptr, qkv, 4096, 3072, 1024, 1);
  // vT = (V slice of qkv)^T
  transpose_b2b_kernel<<<dim3(32, 128), tb, 0, stream>>>(qkv + 2048, vT, 3072, 4096);
  // attention -> ob (bf16)
  attn_kernel<<<dim3(32, 16, 2), 256, 0, stream>>>(qkv, vT, ob);
  // aout partials = ob @ Wo  (f32, split-K=2) — 1024 blocks, 4/CU
  gemm_bt_n64<<<dim3(16, 32, 2), 256, 0, stream>>>(ob, woT, nullptr, aout, 4096, 1024, 1024, 0);
  // x1 = LN(aout0 + aout1 + x): bf16 (FFN1 operand) + f32 (LN2 residual)
  ln_kernel<<<4096, 256, 0, stream>>>(aout, aout + 4194304, x, nullptr, g1, bb1, x1, x1f);
  // lazy weight transposes into dead regions
  transpose_f2b_kernel<<<dim3(128, 32, 1), tb, 0, stream>>>(W1, w1T, 1024, 4096, 1024);
  transpose_f2b_kernel<<<dim3(32, 128, 1), tb, 0, stream>>>(W2, w2T, 4096, 1024, 4096);
  // hbuf = relu(x1 @ W1 + b1)  (bf16 out)
  gemm_bt<<<dim3(32, 32), 256, 0, stream>>>(x1, w1T, bias1, hbuf, 4096, 4096, 1024, 1 | 2 | 4);
  // ffn partials = hbuf @ W2  (f32, split-K=2; bias2 folded into LN2)
  gemm_bt_n64<<<dim3(16, 32, 2), 256, 0, stream>>>(hbuf, w2T, nullptr, ffn, 4096, 1024, 4096, 0);
  // out = LN(ffn0 + ffn1 + bias2 + x1f) -> f32 d_out
  ln_kernel<<<4096, 256, 0, stream>>>(ffn, ffn + 4194304, x1f, bias2, g2, bb2, nullptr, (float*)d_out);
}

// Round 3
// 395.223 us; speedup vs baseline: 1.0194x; 1.0194x over previous
//
#include <hip/hip_runtime.h>
#include <hip/hip_bf16.h>

typedef unsigned short u16;
typedef unsigned int u32;
typedef short short8 __attribute__((ext_vector_type(8)));
typedef float fx4 __attribute__((ext_vector_type(4)));
typedef u32 ux4 __attribute__((ext_vector_type(4)));

__device__ __forceinline__ float b2f(u16 x) {
  return __uint_as_float(((u32)x) << 16);
}
__device__ __forceinline__ u16 f2b(float f) {
  u32 u = __float_as_uint(f);
  u += 0x7fffu + ((u >> 16) & 1u);  // RNE
  return (u16)(u >> 16);
}
// HW packed f32x2 -> bf16x2 (RNE). No builtin on gfx950; inline asm per T12.
__device__ __forceinline__ u32 cvtpk(float a, float b) {
  u32 r;
  asm("v_cvt_pk_bf16_f32 %0, %1, %2" : "=v"(r) : "v"(a), "v"(b));
  return r;
}

// Async global->LDS DMA. LDS dest = wave-uniform base + lane*size.
__device__ __forceinline__ void load16(const u16* g, u16* l) {
  __builtin_amdgcn_global_load_lds(
      (__attribute__((address_space(1))) void*)(u16*)g,
      (__attribute__((address_space(3))) void*)l, 16, 0, 0);
}
__device__ __forceinline__ void load4(const u16* g, u16* l) {
  __builtin_amdgcn_global_load_lds(
      (__attribute__((address_space(1))) void*)(u16*)g,
      (__attribute__((address_space(3))) void*)l, 4, 0, 0);
}

// ---------------------------------------------------------------------------
// f32 -> bf16 elementwise. grid = n/1024, block 256 (4 elems/thread).
// ---------------------------------------------------------------------------
__global__ __launch_bounds__(256) void cvt_f2b_kernel(
    const float* __restrict__ in, u16* __restrict__ out)
{
  int i = (blockIdx.x * 256 + threadIdx.x) * 4;
  fx4 v = *(const fx4*)(in + i);
  u16 o4[4];
#pragma unroll
  for (int j = 0; j < 4; ++j) o4[j] = f2b(v[j]);
  *(uint2*)(out + i) = *(uint2*)o4;
}

// ---------------------------------------------------------------------------
// Fused transpose + f32->bf16: out[batch][c][r] = bf16(in[batch][r][c]).
// grid: (C/32, R/32, nbatch), block: (32,8). out batch stride = C * out_ld.
// ---------------------------------------------------------------------------
__global__ __launch_bounds__(256) void transpose_f2b_kernel(
    const float* __restrict__ in, u16* __restrict__ out,
    int R, int C, int out_ld)
{
  __shared__ __align__(16) u16 tile[32][33];
  int tx = threadIdx.x, ty = threadIdx.y;
  int c0 = blockIdx.x * 32, r0 = blockIdx.y * 32;
  const float* inb = in + (size_t)blockIdx.z * R * C;
  u16* outb = out + (size_t)blockIdx.z * C * out_ld;
#pragma unroll
  for (int i = 0; i < 4; ++i)
    tile[ty + i * 8][tx] = f2b(inb[(size_t)(r0 + ty + i * 8) * C + c0 + tx]);
  __syncthreads();
#pragma unroll
  for (int i = 0; i < 4; ++i)
    outb[(size_t)(c0 + ty + i * 8) * out_ld + r0 + tx] = tile[tx][ty + i * 8];
}

// ---------------------------------------------------------------------------
// bf16 strided transpose: out[c][r] = in[r*in_ld + c]. grid (C/32, R/32).
// ---------------------------------------------------------------------------
__global__ __launch_bounds__(256) void transpose_b2b_kernel(
    const u16* __restrict__ in, u16* __restrict__ out, int in_ld, int out_ld)
{
  __shared__ __align__(16) u16 tile[32][33];
  int tx = threadIdx.x, ty = threadIdx.y;
  int c0 = blockIdx.x * 32, r0 = blockIdx.y * 32;
#pragma unroll
  for (int i = 0; i < 4; ++i)
    tile[ty + i * 8][tx] = in[(size_t)(r0 + ty + i * 8) * in_ld + c0 + tx];
  __syncthreads();
#pragma unroll
  for (int i = 0; i < 4; ++i)
    out[(size_t)(c0 + ty + i * 8) * out_ld + r0 + tx] = tile[tx][ty + i * 8];
}

// ---------------------------------------------------------------------------
// C[M,N] = A[M,K] * BT[N,K]^T; bf16 in, fp32 acc. 128x128 tile, BK=32,
// 4 waves x 64x64. global_load_lds dbuf staging, 1 barrier/K-tile, XOR swizzle.
// flags: 1 = store bf16 (else fp32), 2 = add f32 bias[col], 4 = relu.
// ---------------------------------------------------------------------------
__global__ __launch_bounds__(256, 2) void gemm_bt(
    const u16* __restrict__ A, const u16* __restrict__ BT,
    const float* __restrict__ bias, void* __restrict__ Cp,
    int M, int N, int K, int flags)
{
  __shared__ __align__(16) u16 As[2][4096];
  __shared__ __align__(16) u16 Bs[2][4096];
  int tid = threadIdx.x;
  int lane = tid & 63, wid = tid >> 6;
  int l15 = lane & 15, quad = lane >> 4;
  int wm = wid >> 1, wn = wid & 1;
  int m0 = blockIdx.y * 128, n0 = blockIdx.x * 128;

  int srow = wid * 16 + (lane >> 2);
  int sswz = (((lane >> 2) & 3) + ((lane >> 4) & 3)) & 3;
  int gch = (lane & 3) ^ sswz;
  const u16* gA = A + (size_t)(m0 + srow) * K + gch * 8;
  const u16* gB = BT + (size_t)(n0 + srow) * K + gch * 8;
  size_t gstep = (size_t)64 * K;
  u16* lA = &As[0][wid * 512];
  u16* lB = &Bs[0][wid * 512];

  int rswz = ((l15 & 3) + (l15 >> 2)) & 3;
  int rphys = ((quad ^ rswz) & 3) << 3;

  fx4 acc[4][4];
#pragma unroll
  for (int i = 0; i < 4; ++i)
#pragma unroll
    for (int j = 0; j < 4; ++j) acc[i][j] = fx4{0.f, 0.f, 0.f, 0.f};

  int nt = K >> 5;
  load16(gA,         lA);
  load16(gA + gstep, lA + 2048);
  load16(gB,         lB);
  load16(gB + gstep, lB + 2048);

  for (int kt = 0; kt < nt; ++kt) {
    __syncthreads();
    if (kt + 1 < nt) {
      int buf = (kt + 1) & 1;
      const u16* ga = gA + (kt + 1) * 32;
      const u16* gb = gB + (kt + 1) * 32;
      load16(ga,         lA + buf * 4096);
      load16(ga + gstep, lA + buf * 4096 + 2048);
      load16(gb,         lB + buf * 4096);
      load16(gb + gstep, lB + buf * 4096 + 2048);
    }
    const u16* Ab = As[kt & 1];
    const u16* Bb = Bs[kt & 1];
    short8 af[4], bf[4];
#pragma unroll
    for (int t = 0; t < 4; ++t)
      af[t] = *(const short8*)&Ab[(wm * 64 + t * 16 + l15) * 32 + rphys];
#pragma unroll
    for (int t = 0; t < 4; ++t)
      bf[t] = *(const short8*)&Bb[(wn * 64 + t * 16 + l15) * 32 + rphys];
#pragma unroll
    for (int tm = 0; tm < 4; ++tm)
#pragma unroll
      for (int tn = 0; tn < 4; ++tn)
        acc[tm][tn] = __builtin_amdgcn_mfma_f32_16x16x32_bf16(
            af[tm], bf[tn], acc[tm][tn], 0, 0, 0);
  }

  bool obf = flags & 1, hb = flags & 2, rl = flags & 4;
#pragma unroll
  for (int tn = 0; tn < 4; ++tn) {
    int col = n0 + wn * 64 + tn * 16 + l15;
    float bv = hb ? bias[col] : 0.0f;
#pragma unroll
    for (int tm = 0; tm < 4; ++tm) {
      int row = m0 + wm * 64 + tm * 16 + (quad << 2);
#pragma unroll
      for (int r = 0; r < 4; ++r) {
        float v = acc[tm][tn][r] + bv;
        if (rl) v = fmaxf(v, 0.0f);
        size_t idx = (size_t)(row + r) * N + col;
        if (obf) ((u16*)Cp)[idx] = f2b(v);
        else ((float*)Cp)[idx] = v;
      }
    }
  }
}

// ---------------------------------------------------------------------------
// 128M x 64N tile variant for small-N GEMMs, with split-K over blockIdx.z.
// Each z-chunk computes C_z = A[:, z*kc:(z+1)*kc] * BT[:, same]^T and writes
// its own f32 partial buffer at Cp + z*M*N floats (summed later in ln_kernel).
// 4 waves x 64x32 (4x2 mfma tiles), 24 KB LDS -> 4+ blocks/CU co-resident.
// grid: (N/64, M/128, nsplit). Same flags as gemm_bt.
// ---------------------------------------------------------------------------
__global__ __launch_bounds__(256, 2) void gemm_bt_n64(
    const u16* __restrict__ A, const u16* __restrict__ BT,
    const float* __restrict__ bias, void* __restrict__ Cp,
    int M, int N, int K, int flags)
{
  __shared__ __align__(16) u16 As[2][4096];
  __shared__ __align__(16) u16 Bs[2][2048];
  int tid = threadIdx.x;
  int lane = tid & 63, wid = tid >> 6;
  int l15 = lane & 15, quad = lane >> 4;
  int wm = wid >> 1, wn = wid & 1;
  int m0 = blockIdx.y * 128, n0 = blockIdx.x * 64;
  int zz = blockIdx.z;
  int kc = K / (int)gridDim.z;  // K-chunk length (multiple of 32)

  int srow = wid * 16 + (lane >> 2);
  int sswz = (((lane >> 2) & 3) + ((lane >> 4) & 3)) & 3;
  int gch = (lane & 3) ^ sswz;
  const u16* gA = A + (size_t)(m0 + srow) * K + zz * kc + gch * 8;
  const u16* gB = BT + (size_t)(n0 + srow) * K + zz * kc + gch * 8;
  size_t gstep = (size_t)64 * K;
  u16* lA = &As[0][wid * 512];
  u16* lB = &Bs[0][wid * 512];

  int rswz = ((l15 & 3) + (l15 >> 2)) & 3;
  int rphys = ((quad ^ rswz) & 3) << 3;

  fx4 acc[4][2];
#pragma unroll
  for (int i = 0; i < 4; ++i)
#pragma unroll
    for (int j = 0; j < 2; ++j) acc[i][j] = fx4{0.f, 0.f, 0.f, 0.f};

  int nt = kc >> 5;
  load16(gA,         lA);
  load16(gA + gstep, lA + 2048);
  load16(gB,         lB);

  for (int kt = 0; kt < nt; ++kt) {
    __syncthreads();
    if (kt + 1 < nt) {
      int buf = (kt + 1) & 1;
      const u16* ga = gA + (kt + 1) * 32;
      const u16* gb = gB + (kt + 1) * 32;
      load16(ga,         lA + buf * 4096);
      load16(ga + gstep, lA + buf * 4096 + 2048);
      load16(gb,         lB + buf * 2048);
    }
    const u16* Ab = As[kt & 1];
    const u16* Bb = Bs[kt & 1];
    short8 af[4], bf[2];
#pragma unroll
    for (int t = 0; t < 4; ++t)
      af[t] = *(const short8*)&Ab[(wm * 64 + t * 16 + l15) * 32 + rphys];
#pragma unroll
    for (int t = 0; t < 2; ++t)
      bf[t] = *(const short8*)&Bb[(wn * 32 + t * 16 + l15) * 32 + rphys];
#pragma unroll
    for (int tm = 0; tm < 4; ++tm)
#pragma unroll
      for (int tn = 0; tn < 2; ++tn)
        acc[tm][tn] = __builtin_amdgcn_mfma_f32_16x16x32_bf16(
            af[tm], bf[tn], acc[tm][tn], 0, 0, 0);
  }

  bool obf = flags & 1, hb = flags & 2, rl = flags & 4;
  u16* cb16 = (u16*)Cp + (size_t)zz * M * N;
  float* cf32 = (float*)Cp + (size_t)zz * M * N;
#pragma unroll
  for (int tn = 0; tn < 2; ++tn) {
    int col = n0 + wn * 32 + tn * 16 + l15;
    float bv = hb ? bias[col] : 0.0f;
#pragma unroll
    for (int tm = 0; tm < 4; ++tm) {
      int row = m0 + wm * 64 + tm * 16 + (quad << 2);
#pragma unroll
      for (int r = 0; r < 4; ++r) {
        float v = acc[tm][tn][r] + bv;
        if (rl) v = fmaxf(v, 0.0f);
        size_t idx = (size_t)(row + r) * N + col;
        if (obf) cb16[idx] = f2b(v);
        else cf32[idx] = v;
      }
    }
  }
}

// ---------------------------------------------------------------------------
// Flash attention v2, in-register P, permuted-V LDS staging.
// qkv[4096][3072] bf16 (q|k|v); vT[1024][4096] bf16; o[4096][1024] bf16.
// grid: (S/64, H, B); block 256. 64-key tiles, global_load_lds dbuf.
// QK^T computed SWAPPED (mfma(K,Q)) so P[key][q=l15] is lane-local; the 16
// p-values cvt_pk directly into the PV A-fragment under the permuted key axis
// pi(q*8+j) = (j<4) ? q*4+j : 16+q*4+(j-4).
// V is staged into LDS ALREADY PERMUTED+XOR-SWIZZLED via size-4
// global_load_lds with pre-permuted per-lane source addresses, so the PV
// B-fragment reads are plain ds_read_b128 (same conflict-free pattern as K).
// Row sums: per-lane f32 accumulate + shfl reduce at the end.
// ---------------------------------------------------------------------------
__global__ __launch_bounds__(256) void attn_kernel(
    const u16* __restrict__ qkv, const u16* __restrict__ vT,
    u16* __restrict__ o)
{
  __shared__ __align__(16) u16 Ks[2][4096];
  __shared__ __align__(16) u16 Vs[2][4096];
  int tid = threadIdx.x;
  int lane = tid & 63, wid = tid >> 6;
  int l15 = lane & 15, quad = lane >> 4;
  int b = blockIdx.z, h = blockIdx.y;
  int q0 = blockIdx.x * 64 + wid * 16;

  const u16* qb = qkv + (size_t)(b * 2048 + q0 + l15) * 3072 + h * 64 + (quad << 3);
  short8 qf0 = *(const short8*)qb;
  short8 qf1 = *(const short8*)(qb + 32);

  // K staging: 16B/lane, XOR-swizzled source columns (rows = keys, 64 u16/row)
  int srow = tid >> 3;
  int gc8 = ((tid & 7) ^ (srow & 7)) << 3;
  const u16* kg = qkv + (size_t)(b * 2048 + srow) * 3072 + 1024 + h * 64 + gc8;
  u16* lk = &Ks[0][wid * 512];

  // V staging: 4B/lane, pre-permuted + XOR-swizzled source dwords.
  // Dest (linear) dword g = k*256 + tid -> row d = k*8 + (tid>>5), col dword
  // m_phys = tid&31. Stored content: logical chunk = phys chunk ^ (d&7);
  // logical dword m maps to source dword fdw = perm(m) of the 64-key row.
  int r8 = tid >> 5;
  int m_phys = tid & 31;
  int c_log = ((m_phys >> 2) ^ r8) & 7;
  int m_log = (c_log << 2) | (m_phys & 3);
  int m16 = m_log & 15;
  int qd = m16 >> 2, td = m16 & 3;
  int p16 = (td < 2) ? (qd * 2 + td) : (8 + qd * 2 + td - 2);
  int fdw = (m_log & 16) + p16;
  const u16* vg = vT + (size_t)(h * 64 + r8) * 4096 + b * 2048 + fdw * 2;
  u16* lvw = &Vs[0][wid * 128];  // + k*512 per sub-load, + buf*4096

  fx4 oacc[4];
  float suml = 0.0f;
#pragma unroll
  for (int i = 0; i < 4; ++i) oacc[i] = fx4{0.f, 0.f, 0.f, 0.f};

  load16(kg,             lk);
  load16(kg + 32 * 3072, lk + 2048);
#pragma unroll
  for (int k = 0; k < 8; ++k) load4(vg + (size_t)k * 8 * 4096, lvw + k * 512);

  int swz = l15 & 7;
  for (int kt = 0; kt < 32; ++kt) {
    __syncthreads();
    if (kt + 1 < 32) {
      int buf = (kt + 1) & 1;
      const u16* kgn = kg + (size_t)(kt + 1) * 64 * 3072;
      const u16* vgn = vg + (kt + 1) * 64;
      load16(kgn,             lk + buf * 4096);
      load16(kgn + 32 * 3072, lk + buf * 4096 + 2048);
#pragma unroll
      for (int k = 0; k < 8; ++k)
        load4(vgn + (size_t)k * 8 * 4096, lvw + buf * 4096 + k * 512);
    }
    const u16* Kb = Ks[kt & 1];
    const u16* Vb = Vs[kt & 1];

    // QK^T swapped: sc[sub][r] = S[key = sub*16 + quad*4 + r][q = l15]
    fx4 sc[4];
#pragma unroll
    for (int sub = 0; sub < 4; ++sub) {
      sc[sub] = fx4{0.f, 0.f, 0.f, 0.f};
      const u16* rp = &Kb[(sub * 16 + l15) * 64];
      short8 kf0 = *(const short8*)&rp[((quad ^ swz) & 7) << 3];
      short8 kf1 = *(const short8*)&rp[(((4 | quad) ^ swz) & 7) << 3];
      sc[sub] = __builtin_amdgcn_mfma_f32_16x16x32_bf16(kf0, qf0, sc[sub], 0, 0, 0);
      sc[sub] = __builtin_amdgcn_mfma_f32_16x16x32_bf16(kf1, qf1, sc[sub], 0, 0, 0);
    }

    // softmax numerators straight into PV A-fragments (in-register)
    u32 W[4][2];
    float ps = 0.0f;
#pragma unroll
    for (int sub = 0; sub < 4; ++sub) {
      float p0 = __expf(sc[sub][0] * 0.125f);
      float p1 = __expf(sc[sub][1] * 0.125f);
      float p2 = __expf(sc[sub][2] * 0.125f);
      float p3 = __expf(sc[sub][3] * 0.125f);
      ps += (p0 + p1) + (p2 + p3);
      W[sub][0] = cvtpk(p0, p1);
      W[sub][1] = cvtpk(p2, p3);
    }
    suml += ps;
    short8 pa1 = __builtin_bit_cast(short8, ux4{W[0][0], W[0][1], W[1][0], W[1][1]});
    short8 pa2 = __builtin_bit_cast(short8, ux4{W[2][0], W[2][1], W[3][0], W[3][1]});

    // PV: b128 fragment reads from permuted V (same pattern as K: conflict-free)
#pragma unroll
    for (int dt = 0; dt < 4; ++dt) {
      const u16* rp = &Vb[(dt * 16 + l15) * 64];
      short8 vf0 = *(const short8*)&rp[((quad ^ swz) & 7) << 3];
      short8 vf1 = *(const short8*)&rp[(((4 | quad) ^ swz) & 7) << 3];
      oacc[dt] = __builtin_amdgcn_mfma_f32_16x16x32_bf16(pa1, vf0, oacc[dt], 0, 0, 0);
      oacc[dt] = __builtin_amdgcn_mfma_f32_16x16x32_bf16(pa2, vf1, oacc[dt], 0, 0, 0);
    }
  }
  // denominator: reduce the 4 quads sharing each l15, then fetch per-row
  suml += __shfl_xor(suml, 16, 64);
  suml += __shfl_xor(suml, 32, 64);
  fx4 inv;
#pragma unroll
  for (int r = 0; r < 4; ++r)
    inv[r] = 1.0f / __shfl(suml, (quad << 2) + r, 64);
#pragma unroll
  for (int dt = 0; dt < 4; ++dt) {
    int col = h * 64 + dt * 16 + l15;
#pragma unroll
    for (int r = 0; r < 4; ++r)
      o[(size_t)(b * 2048 + q0 + (quad << 2) + r) * 1024 + col] =
          f2b(oacc[dt][r] * inv[r]);
  }
}

// ---------------------------------------------------------------------------
// LN: LayerNorm(main0 + main1 + res + cbias[col]) * g + beta, row len 1024.
// main1 is the second split-K partial (always present); cbias nullable
// (folds the FFN2 column bias in, since the GEMM now emits raw partials).
// ---------------------------------------------------------------------------
__global__ __launch_bounds__(256) void ln_kernel(
    const float* __restrict__ main0, const float* __restrict__ main1,
    const float* __restrict__ res, const float* __restrict__ cbias,
    const float* __restrict__ g, const float* __restrict__ beta,
    u16* __restrict__ out_b, float* __restrict__ out_f)
{
  __shared__ float red[8];
  int row = blockIdx.x, tid = threadIdx.x;
  size_t base = (size_t)row * 1024 + tid * 4;
  fx4 v = *(const fx4*)(main0 + base);
  fx4 v1 = *(const fx4*)(main1 + base);
  fx4 rv = *(const fx4*)(res + base);
#pragma unroll
  for (int i = 0; i < 4; ++i) v[i] += v1[i] + rv[i];
  if (cbias) {
    fx4 cb = *(const fx4*)(cbias + tid * 4);
#pragma unroll
    for (int i = 0; i < 4; ++i) v[i] += cb[i];
  }
  float s = v[0] + v[1] + v[2] + v[3];
  float sq = v[0] * v[0] + v[1] * v[1] + v[2] * v[2] + v[3] * v[3];
#pragma unroll
  for (int off = 32; off >= 1; off >>= 1) {
    s += __shfl_xor(s, off, 64);
    sq += __shfl_xor(sq, off, 64);
  }
  int wid = tid >> 6, lane = tid & 63;
  if (lane == 0) { red[wid] = s; red[wid + 4] = sq; }
  __syncthreads();
  float S = red[0] + red[1] + red[2] + red[3];
  float SQ = red[4] + red[5] + red[6] + red[7];
  float mean = S * (1.0f / 1024.0f);
  float var = SQ * (1.0f / 1024.0f) - mean * mean;
  float rs = rsqrtf(var + 1e-5f);
  fx4 gv = *(const fx4*)(g + tid * 4);
  fx4 bv = *(const fx4*)(beta + tid * 4);
  float of[4];
#pragma unroll
  for (int i = 0; i < 4; ++i) of[i] = (v[i] - mean) * rs * gv[i] + bv[i];
  if (out_f) *(fx4*)(out_f + base) = *(const fx4*)of;
  if (out_b) {
    u16 o4[4];
#pragma unroll
    for (int i = 0; i < 4; ++i) o4[i] = f2b(of[i]);
    *(uint2*)(out_b + base) = *(uint2*)o4;
  }
}

// ---------------------------------------------------------------------------
// Workspace (peak 88 MiB, liveness-checked):
//   xb    bf16 [ 0, 8)M   (dead after QKV gemm)
//   wqkvT bf16 [ 8,14)M   (dead after QKV gemm)
//   woT   bf16 [38,40)M   (dead after Wo-proj)
//   qkv   bf16 [40,64)M   (dead after attn)
//   vT    bf16 [64,72)M   (dead after attn)
//   ob    bf16 [72,80)M   (dead after Wo-proj)
//   aout  f32  [ 0,32)M   2 split-K partials (dead after LN1)
//   x1f   f32  [40,56)M   (live until LN2)
//   x1    bf16 [64,72)M   (dead after FFN1)
//   w1T   bf16 [56,64)M   (dead after FFN1)
//   w2T   bf16 [ 0, 8)M   (live until FFN2)
//   hbuf  bf16 [ 8,40)M   (live until FFN2)
//   ffn   f32  [56,88)M   2 split-K partials (live until LN2)
// ---------------------------------------------------------------------------
extern "C" void kernel_launch(void* const* d_in, const int* in_sizes, int n_in,
                              void* d_out, int out_size, void* d_ws, size_t ws_size,
                              hipStream_t stream) {
  (void)in_sizes; (void)n_in; (void)out_size; (void)ws_size;
  const float* x     = (const float*)d_in[0];
  const float* Wq    = (const float*)d_in[1];
  const float* Wk    = (const float*)d_in[2];
  const float* Wv    = (const float*)d_in[3];
  const float* Wo    = (const float*)d_in[4];
  const float* g1    = (const float*)d_in[5];
  const float* bb1   = (const float*)d_in[6];
  const float* W1    = (const float*)d_in[7];
  const float* bias1 = (const float*)d_in[8];
  const float* W2    = (const float*)d_in[9];
  const float* bias2 = (const float*)d_in[10];
  const float* g2    = (const float*)d_in[11];
  const float* bb2   = (const float*)d_in[12];

  char* ws = (char*)d_ws;
  const size_t MB = 1048576;
  u16* xb     = (u16*)(ws);
  u16* wqkvT  = (u16*)(ws + 8 * MB);
  u16* woT    = (u16*)(ws + 38 * MB);
  u16* qkv    = (u16*)(ws + 40 * MB);
  u16* vT     = (u16*)(ws + 64 * MB);
  u16* ob     = (u16*)(ws + 72 * MB);
  float* aout = (float*)(ws);            // 2 partials, 16MB each
  u16* x1     = (u16*)(ws + 64 * MB);
  float* x1f  = (float*)(ws + 40 * MB);
  u16* w1T    = (u16*)(ws + 56 * MB);
  u16* w2T    = (u16*)(ws);
  u16* hbuf   = (u16*)(ws + 8 * MB);
  float* ffn  = (float*)(ws + 56 * MB);  // 2 partials, 16MB each

  dim3 tb(32, 8, 1);
  cvt_f2b_kernel<<<4096, 256, 0, stream>>>(x, xb);
  transpose_f2b_kernel<<<dim3(2, 32, 16), tb, 0, stream>>>(Wq, wqkvT,           1024, 64, 1024);
  transpose_f2b_kernel<<<dim3(2, 32, 16), tb, 0, stream>>>(Wk, wqkvT + 1048576, 1024, 64, 1024);
  transpose_f2b_kernel<<<dim3(2, 32, 16), tb, 0, stream>>>(Wv, wqkvT + 2097152, 1024, 64, 1024);
  transpose_f2b_kernel<<<dim3(32, 32, 1), tb, 0, stream>>>(Wo, woT, 1024, 1024, 1024);

  // qkv = x @ [Wq|Wk|Wv]  (bf16 out)
  gemm_bt<<<dim3(24, 32), 256, 0, stream>>>(xb, wqkvT, nullptr, qkv, 4096, 3072, 1024, 1);
  // vT = (V slice of qkv)^T
  transpose_b2b_kernel<<<dim3(32, 128), tb, 0, stream>>>(qkv + 2048, vT, 3072, 4096);
  // attention -> ob (bf16)
  attn_kernel<<<dim3(32, 16, 2), 256, 0, stream>>>(qkv, vT, ob);
  // aout partials = ob @ Wo  (f32, split-K=2) — 1024 blocks, 4/CU
  gemm_bt_n64<<<dim3(16, 32, 2), 256, 0, stream>>>(ob, woT, nullptr, aout, 4096, 1024, 1024, 0);
  // x1 = LN(aout0 + aout1 + x): bf16 (FFN1 operand) + f32 (LN2 residual)
  ln_kernel<<<4096, 256, 0, stream>>>(aout, aout + 4194304, x, nullptr, g1, bb1, x1, x1f);
  // lazy weight transposes into dead regions
  transpose_f2b_kernel<<<dim3(128, 32, 1), tb, 0, stream>>>(W1, w1T, 1024, 4096, 1024);
  transpose_f2b_kernel<<<dim3(32, 128, 1), tb, 0, stream>>>(W2, w2T, 4096, 1024, 4096);
  // hbuf = relu(x1 @ W1 + b1)  (bf16 out)
  gemm_bt<<<dim3(32, 32), 256, 0, stream>>>(x1, w1T, bias1, hbuf, 4096, 4096, 1024, 1 | 2 | 4);
  // ffn partials = hbuf @ W2  (f32, split-K=2; bias2 folded into LN2)
  gemm_bt_n64<<<dim3(16, 32, 2), 256, 0, stream>>>(hbuf, w2T, nullptr, ffn, 4096, 1024, 4096, 0);
  // out = LN(ffn0 + ffn1 + bias2 + x1f) -> f32 d_out
  ln_kernel<<<4096, 256, 0, stream>>>(ffn, ffn + 4194304, x1f, bias2, g2, bb2, nullptr, (float*)d_out);
}